// Round 5
// baseline (441.191 us; speedup 1.0000x reference)
//
#include <hip/hip_runtime.h>
#include <math.h>

// Problem constants (from reference):
//   x: (16, 256, 128, 128) fp32 ; w: (8, 32, 32) fp32 ; logdet: (16,) fp32
//   z[b, k*32+d, h, w] = sum_c W[k][d][c] * x[b, k*32+c, h, w]
//   out = [z flat (67108864 floats)] ++ [logdet + sum_k log|det W_k| * 16384  (16 floats)]
#define HW    16384   // 128*128
#define NB    8
#define BC    32
#define BATCH 16
#define Z_ELEMS (16 * 256 * HW)   // 67108864

// Native Clang vector type: required by __builtin_nontemporal_load/store
typedef float v4f __attribute__((ext_vector_type(4)));

// ---------------------------------------------------------------------------
// Fused kernel. grid = 1025 blocks x 512 threads.
//   block 0       : logdet of the 8 32x32 blocks (first 4 waves), register-
//                   resident LU with shfl-butterfly pivoting; hides under conv.
//                   Barrier is at block scope (uniform across all 512 threads
//                   -- no divergent __syncthreads).
//   blocks 1..1024: block-diagonal 1x1 conv, acc-stationary 2-deep prefetch
//                   (round-2 structure, best measured). 512-thread blocks:
//                   each block covers 2048 contiguous pixels -> 8KB contiguous
//                   per channel stream (vs 4KB at 256 thr) and one block per
//                   CU (160 VGPR -> 8 waves/CU) -> half the concurrent DRAM
//                   streams per CU, double the page locality.
// ---------------------------------------------------------------------------
__global__ __launch_bounds__(512) void fused_kernel(const float* __restrict__ x,
                                                    const float* __restrict__ w,
                                                    const float* __restrict__ ld_in,
                                                    float* __restrict__ out) {
    if (blockIdx.x == 0) {
        const int tid = threadIdx.x;
        __shared__ float ldpart[NB];

        if (tid < 256) {
            // ---------------- logdet path (verified round 2) ----------------
            // 4 waves; each wave: 2 matrices (one per 32-lane half). Lane
            // (half*32+r) owns row r of matrix mi in VGPRs. Virtual partial
            // pivoting (active-mask, no swaps); shfl-butterfly argmax.
            const int wv   = tid >> 6;
            const int lane = tid & 63;
            const int row  = lane & 31;
            const int mi   = (wv << 1) | (lane >> 5);

            float r[BC];
            {
                const float* wr = w + mi * (BC * BC) + row * BC;
                const v4f* wr4 = (const v4f*)wr;
#pragma unroll
                for (int j4 = 0; j4 < BC / 4; ++j4) {
                    v4f v = wr4[j4];
                    r[j4 * 4 + 0] = v.x;
                    r[j4 * 4 + 1] = v.y;
                    r[j4 * 4 + 2] = v.z;
                    r[j4 * 4 + 3] = v.w;
                }
            }

            float ldsum  = 0.f;
            bool  active = true;

#pragma unroll
            for (int t = 0; t < BC; ++t) {
                float cand = active ? fabsf(r[t]) : -1.0f;
                int   idx  = row;
#pragma unroll
                for (int off = 1; off < 32; off <<= 1) {
                    float oc = __shfl_xor(cand, off);
                    int   oi = __shfl_xor(idx, off);
                    if (oc > cand || (oc == cand && oi < idx)) { cand = oc; idx = oi; }
                }
                const int   plane = (lane & 32) | idx;     // absolute pivot lane
                const float pv    = __shfl(r[t], plane);   // signed pivot
                ldsum += logf(cand);                       // cand == |pv|

                const float f = (active && lane != plane) ? (r[t] / pv) : 0.0f;
#pragma unroll
                for (int j = t + 1; j < BC; ++j) {
                    const float pj = __shfl(r[j], plane);
                    r[j] = fmaf(-f, pj, r[j]);
                }
                if (lane == plane) active = false;         // row consumed
            }

            if (row == 0) ldpart[mi] = ldsum;
        }

        __syncthreads();   // uniform: every thread of block 0 reaches this once

        if (tid < BATCH) {
            float tot = 0.f;
#pragma unroll
            for (int i = 0; i < NB; ++i) tot += ldpart[i];
            out[Z_ELEMS + tid] = ld_in[tid] + tot * (float)HW;
        }
        return;
    }

    // ------------------- conv path (round-2 structure) -------------------
    // Each block: 2048 pixels of one (b,k) slice. Each thread: one float4
    // (4 pixel columns), acc[32] in VGPRs, c-loop with 2-deep manual
    // prefetch. Weights are wave-uniform -> scalar loads.
    const int tid = threadIdx.x;
    const int blk = blockIdx.x - 1;
    const int s   = blk >> 3;              // slice id in [0,128): s = b*8 + k
    const int k   = s & 7;                 // weight block
    const int pix = ((blk & 7) << 11) + (tid << 2);

    const size_t base = (size_t)s * (BC * HW);
    const float* xp = x   + base + pix;
    float*       op = out + base + pix;
    const float* wk = w + k * (BC * BC);   // wave-uniform pointer

    v4f acc[BC];
#pragma unroll
    for (int d = 0; d < BC; ++d) acc[d] = (v4f)(0.f);

    // prime the 2-deep pipeline
    v4f cur0 = __builtin_nontemporal_load((const v4f*)(xp));
    v4f cur1 = __builtin_nontemporal_load((const v4f*)(xp + HW));

    for (int c = 0; c < BC; c += 2) {
        v4f nxt0 = (v4f)(0.f), nxt1 = (v4f)(0.f);
        if (c + 2 < BC) {
            nxt0 = __builtin_nontemporal_load((const v4f*)(xp + (size_t)(c + 2) * HW));
            nxt1 = __builtin_nontemporal_load((const v4f*)(xp + (size_t)(c + 3) * HW));
        }
#pragma unroll
        for (int d = 0; d < BC; ++d) {
            const float w0 = wk[d * BC + c];       // uniform -> SGPR
            const float w1 = wk[d * BC + c + 1];   // uniform -> SGPR
            acc[d] += w0 * cur0;
            acc[d] += w1 * cur1;
        }
        cur0 = nxt0;
        cur1 = nxt1;
    }

#pragma unroll
    for (int d = 0; d < BC; ++d) {
        __builtin_nontemporal_store(acc[d], (v4f*)(op + (size_t)d * HW));
    }
}

extern "C" void kernel_launch(void* const* d_in, const int* in_sizes, int n_in,
                              void* d_out, int out_size, void* d_ws, size_t ws_size,
                              hipStream_t stream) {
    const float* x  = (const float*)d_in[0];
    const float* w  = (const float*)d_in[1];
    const float* ld = (const float*)d_in[2];
    float* out = (float*)d_out;

    fused_kernel<<<dim3(1025), dim3(512), 0, stream>>>(x, w, ld, out);
}

// Round 6
// 428.544 us; speedup vs baseline: 1.0295x; 1.0295x over previous
//
#include <hip/hip_runtime.h>
#include <math.h>

// Problem constants (from reference):
//   x: (16, 256, 128, 128) fp32 ; w: (8, 32, 32) fp32 ; logdet: (16,) fp32
//   z[b, k*32+d, h, w] = sum_c W[k][d][c] * x[b, k*32+c, h, w]
//   out = [z flat (67108864 floats)] ++ [logdet + sum_k log|det W_k| * 16384  (16 floats)]
#define HW    16384   // 128*128
#define NB    8
#define BC    32
#define BATCH 16
#define Z_ELEMS (16 * 256 * HW)   // 67108864

// Native Clang vector type: required by __builtin_nontemporal_load/store
typedef float v4f __attribute__((ext_vector_type(4)));

// ---------------------------------------------------------------------------
// Fused kernel. grid = 2049 blocks x 256 threads.  [round-2 verified: 429.4us]
//   block 0      : logdet of the 8 32x32 blocks, register-resident LU with
//                  shfl-butterfly pivoting (hides under the conv blocks).
//   blocks 1..2048: block-diagonal 1x1 conv, acc-stationary, 2-deep prefetch.
// Experiments that regressed (do not redo):
//   - input-stationary 32-deep load burst: 438.0 (latency already hidden at
//     8 waves/CU; Little's law needs ~4.7KB/CU in flight, we have 16KB)
//   - 512-thr blocks for longer DRAM streams: 441.2 (lost inter-block tail
//     overlap; page locality was not a limiter)
// Conv is at the mixed-stream roofline: 537MB @ ~5.8TB/s ~= 93us.
// ---------------------------------------------------------------------------
__global__ __launch_bounds__(256) void fused_kernel(const float* __restrict__ x,
                                                    const float* __restrict__ w,
                                                    const float* __restrict__ ld_in,
                                                    float* __restrict__ out) {
    if (blockIdx.x == 0) {
        // ------------------- logdet path -------------------
        // 4 waves; each wave handles 2 matrices (one per 32-lane half).
        // Lane (half*32 + r) owns row r of matrix mi = wv*2 + half, fully in
        // VGPRs (all indices compile-time via full unroll). Partial pivoting
        // is "virtual": no row swaps, just an active-row mask. log|det| =
        // sum log|pivot| over the 32 elimination steps.
        const int tid  = threadIdx.x;
        const int wv   = tid >> 6;
        const int lane = tid & 63;
        const int row  = lane & 31;
        const int mi   = (wv << 1) | (lane >> 5);

        float r[BC];
        {
            const float* wr = w + mi * (BC * BC) + row * BC;
            const v4f* wr4 = (const v4f*)wr;
#pragma unroll
            for (int j4 = 0; j4 < BC / 4; ++j4) {
                v4f v = wr4[j4];
                r[j4 * 4 + 0] = v.x;
                r[j4 * 4 + 1] = v.y;
                r[j4 * 4 + 2] = v.z;
                r[j4 * 4 + 3] = v.w;
            }
        }

        float ldsum  = 0.f;
        bool  active = true;

#pragma unroll
        for (int t = 0; t < BC; ++t) {
            // argmax |r[t]| over the 32 active rows of this half-wave.
            // shfl_xor with off<32 never crosses the 32-lane half boundary.
            float cand = active ? fabsf(r[t]) : -1.0f;
            int   idx  = row;
#pragma unroll
            for (int off = 1; off < 32; off <<= 1) {
                float oc = __shfl_xor(cand, off);
                int   oi = __shfl_xor(idx, off);
                if (oc > cand || (oc == cand && oi < idx)) { cand = oc; idx = oi; }
            }
            const int   plane = (lane & 32) | idx;        // absolute pivot lane
            const float pv    = __shfl(r[t], plane);      // signed pivot
            ldsum += logf(cand);                          // cand == |pv|

            // eliminate column t from all other active rows (predicated, no
            // divergent branches around the shfls).
            const float f = (active && lane != plane) ? (r[t] / pv) : 0.0f;
#pragma unroll
            for (int j = t + 1; j < BC; ++j) {
                const float pj = __shfl(r[j], plane);
                r[j] = fmaf(-f, pj, r[j]);
            }
            if (lane == plane) active = false;            // row consumed
        }

        __shared__ float ldpart[NB];
        if (row == 0) ldpart[mi] = ldsum;
        __syncthreads();

        if (tid < BATCH) {
            float tot = 0.f;
#pragma unroll
            for (int i = 0; i < NB; ++i) tot += ldpart[i];
            out[Z_ELEMS + tid] = ld_in[tid] + tot * (float)HW;
        }
        return;
    }

    // ------------------- conv path -------------------
    // Each block: 1024 pixels of one (b,k) slice. Each thread: one float4
    // (4 pixel columns), acc[32] in VGPRs, c-loop with 2-deep manual
    // prefetch. Weights are wave-uniform -> scalar loads.
    const int tid = threadIdx.x;
    const int blk = blockIdx.x - 1;
    const int s   = blk >> 4;              // slice id in [0,128): s = b*8 + k
    const int k   = s & 7;                 // weight block
    const int pix = ((blk & 15) << 10) + (tid << 2);

    const size_t base = (size_t)s * (BC * HW);
    const float* xp = x   + base + pix;
    float*       op = out + base + pix;
    const float* wk = w + k * (BC * BC);   // wave-uniform pointer

    v4f acc[BC];
#pragma unroll
    for (int d = 0; d < BC; ++d) acc[d] = (v4f)(0.f);

    // prime the 2-deep pipeline
    v4f cur0 = __builtin_nontemporal_load((const v4f*)(xp));
    v4f cur1 = __builtin_nontemporal_load((const v4f*)(xp + HW));

    for (int c = 0; c < BC; c += 2) {
        v4f nxt0 = (v4f)(0.f), nxt1 = (v4f)(0.f);
        if (c + 2 < BC) {
            nxt0 = __builtin_nontemporal_load((const v4f*)(xp + (size_t)(c + 2) * HW));
            nxt1 = __builtin_nontemporal_load((const v4f*)(xp + (size_t)(c + 3) * HW));
        }
#pragma unroll
        for (int d = 0; d < BC; ++d) {
            const float w0 = wk[d * BC + c];       // uniform -> SGPR
            const float w1 = wk[d * BC + c + 1];   // uniform -> SGPR
            acc[d] += w0 * cur0;
            acc[d] += w1 * cur1;
        }
        cur0 = nxt0;
        cur1 = nxt1;
    }

#pragma unroll
    for (int d = 0; d < BC; ++d) {
        __builtin_nontemporal_store(acc[d], (v4f*)(op + (size_t)d * HW));
    }
}

extern "C" void kernel_launch(void* const* d_in, const int* in_sizes, int n_in,
                              void* d_out, int out_size, void* d_ws, size_t ws_size,
                              hipStream_t stream) {
    const float* x  = (const float*)d_in[0];
    const float* w  = (const float*)d_in[1];
    const float* ld = (const float*)d_in[2];
    float* out = (float*)d_out;

    fused_kernel<<<dim3(2049), dim3(256), 0, stream>>>(x, w, ld, out);
}